// Round 1
// baseline (233.416 us; speedup 1.0000x reference)
//
#include <hip/hip_runtime.h>

typedef unsigned short u16;
typedef unsigned int   u32;
typedef unsigned long long u64;

typedef __attribute__((ext_vector_type(8))) short bf16x8;
typedef __attribute__((ext_vector_type(4))) float f32x4;

__device__ __forceinline__ u16 rne_bf16(float f) {
  u32 u = __builtin_bit_cast(u32, f);
  u = (u + 0x7fffu + ((u >> 16) & 1u)) >> 16;
  return (u16)u;
}
__device__ __forceinline__ u32 pack_bf16x2(float lo, float hi) {
  return (u32)rne_bf16(lo) | ((u32)rne_bf16(hi) << 16);
}

// ---------------- K0: mask row bitmaps + 1/count ----------------
// 8192 rows (64 frames x 128 n). One wave per row.
__global__ __launch_bounds__(256)
void prep_masks(const float* __restrict__ mask,
                u64* __restrict__ bm0, u64* __restrict__ bm1,
                float* __restrict__ invc) {
  int row  = blockIdx.x * 4 + (threadIdx.x >> 6);
  int lane = threadIdx.x & 63;
  float v0 = mask[(long)row * 128 + lane];
  float v1 = mask[(long)row * 128 + 64 + lane];
  u64 b0 = __ballot(v0 == 0.0f);
  u64 b1 = __ballot(v1 == 0.0f);
  if (lane == 0) {
    bm0[row] = b0; bm1[row] = b1;
    int c = __builtin_popcountll(b0) + __builtin_popcountll(b1);
    invc[row] = c ? (1.0f / (float)c) : 0.0f;
  }
}

// ---------------- K1a: WvT[d][j] = qkv_w[1536+j][d]  (fp32 -> bf16) ----------------
__global__ __launch_bounds__(256)
void transpose_wv(const float* __restrict__ qkv_w, u16* __restrict__ WvT) {
  __shared__ float tile[64][65];
  int tj = blockIdx.x % 12, td = blockIdx.x / 12;
  int t = threadIdx.x;
  const float* src = qkv_w + (long)1536 * 768 + (long)(tj * 64) * 768 + td * 64;
  #pragma unroll
  for (int i = 0; i < 4; ++i) {
    int j = (t >> 4) + 16 * i;
    int d = (t & 15) * 4;
    float4 v = *(const float4*)&src[(long)j * 768 + d];
    tile[j][d] = v.x; tile[j][d + 1] = v.y; tile[j][d + 2] = v.z; tile[j][d + 3] = v.w;
  }
  __syncthreads();
  u16* dst = WvT + (long)(td * 64) * 768 + tj * 64;
  #pragma unroll
  for (int i = 0; i < 4; ++i) {
    int d = (t >> 4) + 16 * i;
    int j = (t & 15) * 4;
    uint2 p;
    p.x = pack_bf16x2(tile[j][d],     tile[j + 1][d]);
    p.y = pack_bf16x2(tile[j + 2][d], tile[j + 3][d]);
    *(uint2*)&dst[(long)d * 768 + j] = p;
  }
}

// ---------------- K3: cbias[i] = proj_b[i] + sum_j proj_w[i][j]*qkv_b[1536+j] ----------------
__global__ __launch_bounds__(256)
void bias_combine(const float* __restrict__ proj_w, const float* __restrict__ qkv_b,
                  const float* __restrict__ proj_b, float* __restrict__ cbias) {
  int i = blockIdx.x * 4 + (threadIdx.x >> 6);
  int lane = threadIdx.x & 63;
  float s = 0.f;
  for (int j = lane; j < 768; j += 64) s += proj_w[(long)i * 768 + j] * qkv_b[1536 + j];
  #pragma unroll
  for (int off = 32; off; off >>= 1) s += __shfl_down(s, off);
  if (lane == 0) cbias[i] = s + proj_b[i];
}

// ---------------- GEMM (B^T form): out[m][n] = sum_k A[m][k] * B[n][k] ----------------
// 128x128 tile, 4 waves, BK=32, double-buffered LDS, global_load_lds width 16.
template<bool A_FP32, bool BF16_OUT>
__global__ __launch_bounds__(256, 2)
void gemm_bt(const void* __restrict__ Av, const u16* __restrict__ Bm,
             void* __restrict__ Cv, const float* __restrict__ bias,
             int M, int N, int K, int nblk) {
  __shared__ u16 lA[2][128 * 32];
  __shared__ u16 lB[2][128 * 32];

  const int nwg = gridDim.x;
  const int bid = blockIdx.x;
  // bijective XCD swizzle (m204 form)
  const int qq = nwg >> 3, rr8 = nwg & 7;
  const int xcd = bid & 7, loc = bid >> 3;
  const int swz = (xcd < rr8) ? (xcd * (qq + 1) + loc)
                              : (rr8 * (qq + 1) + (xcd - rr8) * qq + loc);
  const int mb = swz / nblk, nb = swz % nblk;
  const long arow0 = (long)mb * 128;
  const long brow0 = (long)nb * 128;

  const int tid = threadIdx.x;
  const int lane = tid & 63, wid = tid >> 6;
  const int wr = wid >> 1, wc = wid & 1;

  const u16* Ab  = (const u16*)Av;
  const float* Af = (const float*)Av;

  const int nk = K >> 5;

  f32x4 acc[4][4];
  const f32x4 vzero = {0.f, 0.f, 0.f, 0.f};
  #pragma unroll
  for (int i = 0; i < 4; ++i)
    #pragma unroll
    for (int j = 0; j < 4; ++j) acc[i][j] = vzero;

  auto stage = [&](int buf, int kt) {
    #pragma unroll
    for (int i = 0; i < 2; ++i) {
      int tt = tid + 256 * i;
      const u16* g = &Bm[(brow0 + (tt >> 2)) * (long)K + kt * 32 + 8 * (tt & 3)];
      __builtin_amdgcn_global_load_lds(
          static_cast<const u32*>(static_cast<const void*>(g)),
          static_cast<u32*>(static_cast<void*>(&lB[buf][512 * wid + 2048 * i])),
          16, 0, 0);
    }
    if constexpr (A_FP32) {
      #pragma unroll
      for (int i = 0; i < 4; ++i) {
        int row = 32 * i + (tid >> 3);
        int kk = 4 * (tid & 7);
        float4 v = *(const float4*)&Af[(arow0 + row) * (long)K + kt * 32 + kk];
        uint2 p;
        p.x = pack_bf16x2(v.x, v.y);
        p.y = pack_bf16x2(v.z, v.w);
        *(uint2*)&lA[buf][row * 32 + kk] = p;
      }
    } else {
      #pragma unroll
      for (int i = 0; i < 2; ++i) {
        int tt = tid + 256 * i;
        const u16* g = &Ab[(arow0 + (tt >> 2)) * (long)K + kt * 32 + 8 * (tt & 3)];
        __builtin_amdgcn_global_load_lds(
            static_cast<const u32*>(static_cast<const void*>(g)),
            static_cast<u32*>(static_cast<void*>(&lA[buf][512 * wid + 2048 * i])),
            16, 0, 0);
      }
    }
  };

  stage(0, 0);
  __syncthreads();

  int cur = 0;
  for (int kt = 0; kt < nk; ++kt) {
    if (kt + 1 < nk) stage(cur ^ 1, kt + 1);
    bf16x8 afr[4], bfr[4];
    #pragma unroll
    for (int i = 0; i < 4; ++i) {
      afr[i] = *(const bf16x8*)&lA[cur][(64 * wr + 16 * i + (lane & 15)) * 32 + 8 * (lane >> 4)];
      bfr[i] = *(const bf16x8*)&lB[cur][(64 * wc + 16 * i + (lane & 15)) * 32 + 8 * (lane >> 4)];
    }
    #pragma unroll
    for (int mi = 0; mi < 4; ++mi)
      #pragma unroll
      for (int ni = 0; ni < 4; ++ni)
        acc[mi][ni] = __builtin_amdgcn_mfma_f32_16x16x32_bf16(afr[mi], bfr[ni], acc[mi][ni], 0, 0, 0);
    __syncthreads();
    cur ^= 1;
  }

  const long orow = arow0 + 64 * wr;
  const long ocol = brow0 + 64 * wc;
  #pragma unroll
  for (int mi = 0; mi < 4; ++mi) {
    #pragma unroll
    for (int ni = 0; ni < 4; ++ni) {
      #pragma unroll
      for (int e = 0; e < 4; ++e) {
        long row = orow + 16 * mi + 4 * (lane >> 4) + e;
        long col = ocol + 16 * ni + (lane & 15);
        float v = acc[mi][ni][e];
        if constexpr (BF16_OUT) {
          ((u16*)Cv)[row * N + col] = rne_bf16(v);
        } else {
          ((float*)Cv)[row * N + col] = v + bias[col];
        }
      }
    }
  }
}

// ---------------- K2: Z[token][d] = invc[f][n] * sum_{m in maskzero} x[bfi][m][d] ----------------
// grid = 256 bfi x 3 col-chunks of 256; x chunk staged bf16 in LDS.
__global__ __launch_bounds__(256)
void avg_rows(const float* __restrict__ x,
              const u64* __restrict__ bm0, const u64* __restrict__ bm1,
              const float* __restrict__ invc, u16* __restrict__ Z) {
  __shared__ u16 lx[128 * 256];
  __shared__ u64 lb0[128];
  __shared__ u64 lb1[128];
  __shared__ float linv[128];

  const int bid = blockIdx.x;
  const int bfi = bid / 3;
  const int ch  = bid - bfi * 3;
  const int fr  = bfi & 63;
  const int tid = threadIdx.x;
  const int lane = tid & 63;

  const float* xs = x + (long)bfi * 128 * 768 + ch * 256;

  #pragma unroll 4
  for (int rr = 0; rr < 32; ++rr) {
    int row = (tid >> 6) + 4 * rr;
    int c4 = (tid & 63) * 4;
    float4 v = *(const float4*)&xs[(long)row * 768 + c4];
    uint2 p;
    p.x = pack_bf16x2(v.x, v.y);
    p.y = pack_bf16x2(v.z, v.w);
    *(uint2*)&lx[row * 256 + c4] = p;
  }
  if (tid < 128) {
    lb0[tid] = bm0[fr * 128 + tid];
    lb1[tid] = bm1[fr * 128 + tid];
    linv[tid] = invc[fr * 128 + tid];
  }
  __syncthreads();

  const int ng = tid >> 6;
  for (int r = 0; r < 32; ++r) {
    int n = 4 * r + ng;
    u64 m0 = lb0[n], m1 = lb1[n];
    float ic = linv[n];
    float a0 = 0.f, a1 = 0.f, a2 = 0.f, a3 = 0.f;
    while (m0) {
      int m = __builtin_ctzll(m0);
      m0 &= (m0 - 1);
      uint2 wv = *(const uint2*)&lx[m * 256 + lane * 4];
      a0 += __builtin_bit_cast(float, wv.x << 16);
      a1 += __builtin_bit_cast(float, wv.x & 0xffff0000u);
      a2 += __builtin_bit_cast(float, wv.y << 16);
      a3 += __builtin_bit_cast(float, wv.y & 0xffff0000u);
    }
    while (m1) {
      int m = 64 + __builtin_ctzll(m1);
      m1 &= (m1 - 1);
      uint2 wv = *(const uint2*)&lx[m * 256 + lane * 4];
      a0 += __builtin_bit_cast(float, wv.x << 16);
      a1 += __builtin_bit_cast(float, wv.x & 0xffff0000u);
      a2 += __builtin_bit_cast(float, wv.y << 16);
      a3 += __builtin_bit_cast(float, wv.y & 0xffff0000u);
    }
    uint2 o;
    o.x = pack_bf16x2(a0 * ic, a1 * ic);
    o.y = pack_bf16x2(a2 * ic, a3 * ic);
    *(uint2*)&Z[((long)bfi * 128 + n) * 768 + ch * 256 + lane * 4] = o;
  }
}

extern "C" void kernel_launch(void* const* d_in, const int* in_sizes, int n_in,
                              void* d_out, int out_size, void* d_ws, size_t ws_size,
                              hipStream_t stream) {
  (void)in_sizes; (void)n_in; (void)out_size; (void)ws_size;
  const float* x      = (const float*)d_in[0];
  const float* mask   = (const float*)d_in[1];
  // d_in[2] edge_bias: numerically dead (see analysis)
  const float* qkv_w  = (const float*)d_in[3];
  const float* qkv_b  = (const float*)d_in[4];
  const float* proj_w = (const float*)d_in[5];
  const float* proj_b = (const float*)d_in[6];

  char* w = (char*)d_ws;
  u16*   WvT  = (u16*)(w);                 // 768*768*2 = 0x120000
  u16*   Wc   = (u16*)(w + 0x120000);      // 0x120000
  float* cb   = (float*)(w + 0x240000);    // 3 KB
  u64*   bm0  = (u64*)(w + 0x241000);      // 64 KB
  u64*   bm1  = (u64*)(w + 0x251000);      // 64 KB
  float* invc = (float*)(w + 0x261000);    // 32 KB
  u16*   Z    = (u16*)(w + 0x270000);      // 32768*768*2 = 48 MB

  prep_masks<<<dim3(2048), dim3(256), 0, stream>>>(mask, bm0, bm1, invc);
  transpose_wv<<<dim3(144), dim3(256), 0, stream>>>(qkv_w, WvT);
  bias_combine<<<dim3(192), dim3(256), 0, stream>>>(proj_w, qkv_b, proj_b, cb);
  // W_c = proj_w @ Wv : M=N=K=768, 36 blocks
  gemm_bt<true, true><<<dim3(36), dim3(256), 0, stream>>>(
      (const void*)proj_w, WvT, (void*)Wc, nullptr, 768, 768, 768, 6);
  avg_rows<<<dim3(768), dim3(256), 0, stream>>>(x, bm0, bm1, invc, Z);
  // out = Z @ W_c^T + cbias : M=32768, N=768, K=768, 1536 blocks
  gemm_bt<false, false><<<dim3(1536), dim3(256), 0, stream>>>(
      (const void*)Z, Wc, d_out, cb, 32768, 768, 768, 6);
}

// Round 2
// 126.865 us; speedup vs baseline: 1.8399x; 1.8399x over previous
//
#include <hip/hip_runtime.h>

typedef unsigned short u16;
typedef unsigned int   u32;
typedef unsigned long long u64;

typedef __attribute__((ext_vector_type(8))) short bf16x8;
typedef __attribute__((ext_vector_type(4))) float f32x4;

__device__ __forceinline__ u16 rne_bf16(float f) {
  u32 u = __builtin_bit_cast(u32, f);
  u = (u + 0x7fffu + ((u >> 16) & 1u)) >> 16;
  return (u16)u;
}
__device__ __forceinline__ u32 pack_bf16x2(float lo, float hi) {
  return (u32)rne_bf16(lo) | ((u32)rne_bf16(hi) << 16);
}

// ---------------- K0: mask row bitmaps + 1/count ----------------
// 8192 rows (64 frames x 128 n). One wave per row.
__global__ __launch_bounds__(256)
void prep_masks(const float* __restrict__ mask,
                u64* __restrict__ bm0, u64* __restrict__ bm1,
                float* __restrict__ invc) {
  int row  = blockIdx.x * 4 + (threadIdx.x >> 6);
  int lane = threadIdx.x & 63;
  float v0 = mask[(long)row * 128 + lane];
  float v1 = mask[(long)row * 128 + 64 + lane];
  u64 b0 = __ballot(v0 == 0.0f);
  u64 b1 = __ballot(v1 == 0.0f);
  if (lane == 0) {
    bm0[row] = b0; bm1[row] = b1;
    int c = __builtin_popcountll(b0) + __builtin_popcountll(b1);
    invc[row] = c ? (1.0f / (float)c) : 0.0f;
  }
}

// ---------------- K1a: WvT[d][j] = qkv_w[1536+j][d]  (fp32 -> bf16) ----------------
__global__ __launch_bounds__(256)
void transpose_wv(const float* __restrict__ qkv_w, u16* __restrict__ WvT) {
  __shared__ float tile[64][65];
  int tj = blockIdx.x % 12, td = blockIdx.x / 12;
  int t = threadIdx.x;
  const float* src = qkv_w + (long)1536 * 768 + (long)(tj * 64) * 768 + td * 64;
  #pragma unroll
  for (int i = 0; i < 4; ++i) {
    int j = (t >> 4) + 16 * i;
    int d = (t & 15) * 4;
    float4 v = *(const float4*)&src[(long)j * 768 + d];
    tile[j][d] = v.x; tile[j][d + 1] = v.y; tile[j][d + 2] = v.z; tile[j][d + 3] = v.w;
  }
  __syncthreads();
  u16* dst = WvT + (long)(td * 64) * 768 + tj * 64;
  #pragma unroll
  for (int i = 0; i < 4; ++i) {
    int d = (t >> 4) + 16 * i;
    int j = (t & 15) * 4;
    uint2 p;
    p.x = pack_bf16x2(tile[j][d],     tile[j + 1][d]);
    p.y = pack_bf16x2(tile[j + 2][d], tile[j + 3][d]);
    *(uint2*)&dst[(long)d * 768 + j] = p;
  }
}

// ---------------- K3: cbias[i] = proj_b[i] + sum_j proj_w[i][j]*qkv_b[1536+j] ----------------
__global__ __launch_bounds__(256)
void bias_combine(const float* __restrict__ proj_w, const float* __restrict__ qkv_b,
                  const float* __restrict__ proj_b, float* __restrict__ cbias) {
  int i = blockIdx.x * 4 + (threadIdx.x >> 6);
  int lane = threadIdx.x & 63;
  float s = 0.f;
  for (int j = lane; j < 768; j += 64) s += proj_w[(long)i * 768 + j] * qkv_b[1536 + j];
  #pragma unroll
  for (int off = 32; off; off >>= 1) s += __shfl_down(s, off);
  if (lane == 0) cbias[i] = s + proj_b[i];
}

// ---------------- GEMM (B^T form): out[m][n] = sum_k A[m][k] * B[n][k] ----------------
// 128x128 tile, 4 waves, BK=32, double-buffered LDS, global_load_lds width 16.
template<bool A_FP32, bool BF16_OUT>
__global__ __launch_bounds__(256, 2)
void gemm_bt(const void* __restrict__ Av, const u16* __restrict__ Bm,
             void* __restrict__ Cv, const float* __restrict__ bias,
             int M, int N, int K, int nblk) {
  __shared__ u16 lA[2][128 * 32];
  __shared__ u16 lB[2][128 * 32];

  const int nwg = gridDim.x;
  const int bid = blockIdx.x;
  // bijective XCD swizzle (m204 form)
  const int qq = nwg >> 3, rr8 = nwg & 7;
  const int xcd = bid & 7, loc = bid >> 3;
  const int swz = (xcd < rr8) ? (xcd * (qq + 1) + loc)
                              : (rr8 * (qq + 1) + (xcd - rr8) * qq + loc);
  const int mb = swz / nblk, nb = swz % nblk;
  const long arow0 = (long)mb * 128;
  const long brow0 = (long)nb * 128;

  const int tid = threadIdx.x;
  const int lane = tid & 63, wid = tid >> 6;
  const int wr = wid >> 1, wc = wid & 1;

  const u16* Ab  = (const u16*)Av;
  const float* Af = (const float*)Av;

  const int nk = K >> 5;

  f32x4 acc[4][4];
  const f32x4 vzero = {0.f, 0.f, 0.f, 0.f};
  #pragma unroll
  for (int i = 0; i < 4; ++i)
    #pragma unroll
    for (int j = 0; j < 4; ++j) acc[i][j] = vzero;

  auto stage = [&](int buf, int kt) {
    #pragma unroll
    for (int i = 0; i < 2; ++i) {
      int tt = tid + 256 * i;
      const u16* g = &Bm[(brow0 + (tt >> 2)) * (long)K + kt * 32 + 8 * (tt & 3)];
      __builtin_amdgcn_global_load_lds(
          static_cast<const u32*>(static_cast<const void*>(g)),
          static_cast<u32*>(static_cast<void*>(&lB[buf][512 * wid + 2048 * i])),
          16, 0, 0);
    }
    if constexpr (A_FP32) {
      #pragma unroll
      for (int i = 0; i < 4; ++i) {
        int row = 32 * i + (tid >> 3);
        int kk = 4 * (tid & 7);
        float4 v = *(const float4*)&Af[(arow0 + row) * (long)K + kt * 32 + kk];
        uint2 p;
        p.x = pack_bf16x2(v.x, v.y);
        p.y = pack_bf16x2(v.z, v.w);
        *(uint2*)&lA[buf][row * 32 + kk] = p;
      }
    } else {
      #pragma unroll
      for (int i = 0; i < 2; ++i) {
        int tt = tid + 256 * i;
        const u16* g = &Ab[(arow0 + (tt >> 2)) * (long)K + kt * 32 + 8 * (tt & 3)];
        __builtin_amdgcn_global_load_lds(
            static_cast<const u32*>(static_cast<const void*>(g)),
            static_cast<u32*>(static_cast<void*>(&lA[buf][512 * wid + 2048 * i])),
            16, 0, 0);
      }
    }
  };

  stage(0, 0);
  __syncthreads();

  int cur = 0;
  for (int kt = 0; kt < nk; ++kt) {
    if (kt + 1 < nk) stage(cur ^ 1, kt + 1);
    bf16x8 afr[4], bfr[4];
    #pragma unroll
    for (int i = 0; i < 4; ++i) {
      afr[i] = *(const bf16x8*)&lA[cur][(64 * wr + 16 * i + (lane & 15)) * 32 + 8 * (lane >> 4)];
      bfr[i] = *(const bf16x8*)&lB[cur][(64 * wc + 16 * i + (lane & 15)) * 32 + 8 * (lane >> 4)];
    }
    #pragma unroll
    for (int mi = 0; mi < 4; ++mi)
      #pragma unroll
      for (int ni = 0; ni < 4; ++ni)
        acc[mi][ni] = __builtin_amdgcn_mfma_f32_16x16x32_bf16(afr[mi], bfr[ni], acc[mi][ni], 0, 0, 0);
    __syncthreads();
    cur ^= 1;
  }

  const long orow = arow0 + 64 * wr;
  const long ocol = brow0 + 64 * wc;
  #pragma unroll
  for (int mi = 0; mi < 4; ++mi) {
    #pragma unroll
    for (int ni = 0; ni < 4; ++ni) {
      #pragma unroll
      for (int e = 0; e < 4; ++e) {
        long row = orow + 16 * mi + 4 * (lane >> 4) + e;
        long col = ocol + 16 * ni + (lane & 15);
        float v = acc[mi][ni][e];
        if constexpr (BF16_OUT) {
          ((u16*)Cv)[row * N + col] = rne_bf16(v);
        } else {
          ((float*)Cv)[row * N + col] = v + bias[col];
        }
      }
    }
  }
}

// ---------------- K2 (MFMA): Z[bfi][n][d] = invc[f][n] * sum_m M0[f][n][m] * x[bfi][m][d] ----------------
// One block per (bfi, 128-wide d-chunk). M0 expanded from bitmasks into LDS (swizzled),
// x chunk register-transposed into LDS as xT[d][m] bf16 (swizzled). K = m = 128, single shot.
// Swizzle: byte_in_row ^= (row & 15) << 4   (16B-granule permutation of the 256B row).
__global__ __launch_bounds__(256, 2)
void avg_mfma(const float* __restrict__ x,
              const u64* __restrict__ bm0, const u64* __restrict__ bm1,
              const float* __restrict__ invc, u16* __restrict__ Z) {
  __shared__ u16 lM[128 * 128];   // [n][m] swizzled, 32 KB
  __shared__ u16 lx[128 * 128];   // [d][m] swizzled, 32 KB

  const int bid = blockIdx.x;      // 1536 = 256 bfi x 6 chunks
  const int bfi = bid / 6;
  const int ch  = bid - bfi * 6;
  const int fr  = bfi & 63;
  const int tid = threadIdx.x;
  const int lane = tid & 63, wid = tid >> 6;
  const int wr = wid >> 1, wc = wid & 1;

  // --- expand M0 bits -> lM (bf16 {1.0, 0.0}), swizzled ---
  {
    int n = tid >> 1, h = tid & 1;           // 2 threads per row, 64 m each
    u64 bits = h ? bm1[fr * 128 + n] : bm0[fr * 128 + n];
    char* orow = (char*)&lM[n * 128];
    #pragma unroll
    for (int g = 0; g < 8; ++g) {
      u64 w0 = 0, w1 = 0;
      #pragma unroll
      for (int j = 0; j < 4; ++j) {
        if ((bits >> (8 * g + j)) & 1)     w0 |= (u64)0x3f80u << (16 * j);
        if ((bits >> (8 * g + 4 + j)) & 1) w1 |= (u64)0x3f80u << (16 * j);
      }
      int gran = (8 * h + g) ^ (n & 15);
      *(u64*)(orow + gran * 16)     = w0;
      *(u64*)(orow + gran * 16 + 8) = w1;
    }
  }

  // --- register-transpose x chunk -> lx[d][m] bf16, swizzled ---
  {
    const float* xs = x + (long)bfi * 128 * 768 + ch * 128;
    const int dl = tid & 31;       // d within 32-block (consecutive lanes -> consecutive d)
    const int mq = tid >> 5;       // 0..7 (quad-of-m index base)
    #pragma unroll 4
    for (int cc = 0; cc < 16; ++cc) {
      int d  = dl + 32 * (cc & 3);
      int m0 = 4 * (mq + 8 * (cc >> 2));
      float v0 = xs[(long)(m0 + 0) * 768 + d];
      float v1 = xs[(long)(m0 + 1) * 768 + d];
      float v2 = xs[(long)(m0 + 2) * 768 + d];
      float v3 = xs[(long)(m0 + 3) * 768 + d];
      uint2 p;
      p.x = pack_bf16x2(v0, v1);
      p.y = pack_bf16x2(v2, v3);
      int byte = d * 256 + ((m0 * 2) ^ ((d & 15) << 4));
      *(uint2*)((char*)lx + byte) = p;
    }
  }
  __syncthreads();

  // --- MFMA: C[n][d] = sum_m M0[n][m] * xT[d][m], K=128 in 4 steps ---
  f32x4 acc[4][4];
  const f32x4 vzero = {0.f, 0.f, 0.f, 0.f};
  #pragma unroll
  for (int i = 0; i < 4; ++i)
    #pragma unroll
    for (int j = 0; j < 4; ++j) acc[i][j] = vzero;

  #pragma unroll
  for (int kk = 0; kk < 4; ++kk) {
    const int kb = 64 * kk + 16 * (lane >> 4);
    bf16x8 afr[4], bfr[4];
    #pragma unroll
    for (int i = 0; i < 4; ++i) {
      int n = 64 * wr + 16 * i + (lane & 15);
      afr[i] = *(const bf16x8*)((char*)lM + n * 256 + (kb ^ ((n & 15) << 4)));
      int d = 64 * wc + 16 * i + (lane & 15);
      bfr[i] = *(const bf16x8*)((char*)lx + d * 256 + (kb ^ ((d & 15) << 4)));
    }
    #pragma unroll
    for (int mi = 0; mi < 4; ++mi)
      #pragma unroll
      for (int ni = 0; ni < 4; ++ni)
        acc[mi][ni] = __builtin_amdgcn_mfma_f32_16x16x32_bf16(afr[mi], bfr[ni], acc[mi][ni], 0, 0, 0);
  }

  // --- scale by invc (fp32) and store bf16 ---
  const float* icp = invc + fr * 128;
  u16* zp = Z + ((long)bfi * 128) * 768 + ch * 128;
  #pragma unroll
  for (int mi = 0; mi < 4; ++mi) {
    #pragma unroll
    for (int e = 0; e < 4; ++e) {
      int n = 64 * wr + 16 * mi + 4 * (lane >> 4) + e;
      float ic = icp[n];
      #pragma unroll
      for (int ni = 0; ni < 4; ++ni) {
        int d = 64 * wc + 16 * ni + (lane & 15);
        zp[(long)n * 768 + d] = rne_bf16(acc[mi][ni][e] * ic);
      }
    }
  }
}

extern "C" void kernel_launch(void* const* d_in, const int* in_sizes, int n_in,
                              void* d_out, int out_size, void* d_ws, size_t ws_size,
                              hipStream_t stream) {
  (void)in_sizes; (void)n_in; (void)out_size; (void)ws_size;
  const float* x      = (const float*)d_in[0];
  const float* mask   = (const float*)d_in[1];
  // d_in[2] edge_bias: numerically dead (masked entries dominate softmax; rest underflow)
  const float* qkv_w  = (const float*)d_in[3];
  const float* qkv_b  = (const float*)d_in[4];
  const float* proj_w = (const float*)d_in[5];
  const float* proj_b = (const float*)d_in[6];

  char* w = (char*)d_ws;
  u16*   WvT  = (u16*)(w);                 // 768*768*2 = 0x120000
  u16*   Wc   = (u16*)(w + 0x120000);      // 0x120000
  float* cb   = (float*)(w + 0x240000);    // 3 KB
  u64*   bm0  = (u64*)(w + 0x241000);      // 64 KB
  u64*   bm1  = (u64*)(w + 0x251000);      // 64 KB
  float* invc = (float*)(w + 0x261000);    // 32 KB
  u16*   Z    = (u16*)(w + 0x270000);      // 32768*768*2 = 48 MB

  prep_masks<<<dim3(2048), dim3(256), 0, stream>>>(mask, bm0, bm1, invc);
  transpose_wv<<<dim3(144), dim3(256), 0, stream>>>(qkv_w, WvT);
  bias_combine<<<dim3(192), dim3(256), 0, stream>>>(proj_w, qkv_b, proj_b, cb);
  // W_c = proj_w @ Wv : M=N=K=768, 36 blocks
  gemm_bt<true, true><<<dim3(36), dim3(256), 0, stream>>>(
      (const void*)proj_w, WvT, (void*)Wc, nullptr, 768, 768, 768, 6);
  // Z = diag(invc) * (M0 @ x_bf16)  via MFMA
  avg_mfma<<<dim3(1536), dim3(256), 0, stream>>>(x, bm0, bm1, invc, Z);
  // out = Z @ W_c^T + cbias : M=32768, N=768, K=768, 1536 blocks
  gemm_bt<false, false><<<dim3(1536), dim3(256), 0, stream>>>(
      (const void*)Z, Wc, d_out, cb, 32768, 768, 768, 6);
}